// Round 2
// baseline (171.241 us; speedup 1.0000x reference)
//
#include <hip/hip_runtime.h>

// Problem constants (fixed by the reference setup)
#define B_   16
#define C_   64
#define H_   128
#define W_   128
#define HO   126
#define WO   126
#define NK   8     // number of conv kernels
#define ROWS 14    // output rows per block (126 = 9 * 14)
#define INR  16    // input rows staged = ROWS + 2

typedef float f2 __attribute__((ext_vector_type(2)));

// One block per (band, channel, batch). Stage INR x 128 input rows in LDS with
// SiLU pre-applied, then each wave covers one full output row per iteration;
// lane l owns wo = 2l, 2l+1 and writes 8 plane-strided nontemporal dwordx2.
__global__ __launch_bounds__(256) void conv_silu_kernel(
    const float* __restrict__ x, const float* __restrict__ Wt,
    float* __restrict__ out)
{
    __shared__ float s[INR][W_];   // 16 * 128 * 4 B = 8 KiB

    const int band = blockIdx.x;   // 0..8
    const int c    = blockIdx.y;   // 0..63
    const int b    = blockIdx.z;   // 0..15
    const int tid  = threadIdx.x;  // 0..255
    const int ho0  = band * ROWS;

    // Weights: uniform address + constant indices -> scalar loads.
    float w[NK * 9];
#pragma unroll
    for (int i = 0; i < NK * 9; ++i) w[i] = Wt[i];

    // ---- stage input band (16 rows x 128 cols) with SiLU applied ----
    // 2048 floats = 512 float4; 256 threads x 2 each. Always in-bounds:
    // ho0 max = 112, +15 = 127 = H-1.
    const float4* xv = (const float4*)(x + ((size_t)(b * C_ + c) * H_ + ho0) * W_);
#pragma unroll
    for (int i = 0; i < 2; ++i) {
        const int f   = tid + i * 256;     // float4 index 0..511
        const float4 v = xv[f];
        const int row = f >> 5;            // / 32 float4 per row
        const int col = (f & 31) << 2;
        const float vs[4] = {v.x, v.y, v.z, v.w};
#pragma unroll
        for (int q = 0; q < 4; ++q) {
            const float t = vs[q];
            // silu(t) = t / (1 + exp(-t)) ; fast rcp + hw exp
            s[row][col + q] = t * __builtin_amdgcn_rcpf(1.0f + __expf(-t));
        }
    }
    __syncthreads();

    // ---- compute ----
    const int wv = tid >> 6;       // wave 0..3 : row within group-of-4
    const int l  = tid & 63;       // lane
    if (l >= 63) return;           // 63 lanes x 2 = 126 = WO
    const int wo = l << 1;         // 0,2,...,124

    float* op = out + ((size_t)(b * (C_ * NK) + c * NK) * HO + ho0) * WO;

#pragma unroll
    for (int it = 0; it < 4; ++it) {
        const int r = it * 4 + wv;         // rows 0..15; skip >=14
        if (r >= ROWS) break;
        // 3x4 tap window for the two outputs at (r, wo) and (r, wo+1)
        float a[3][4];
#pragma unroll
        for (int dr = 0; dr < 3; ++dr) {
            const float* sp = &s[r + dr][wo];
#pragma unroll
            for (int dc = 0; dc < 4; ++dc) a[dr][dc] = sp[dc];
        }
#pragma unroll
        for (int k = 0; k < NK; ++k) {
            const float* wk = &w[k * 9];
            float acc0 = 0.f, acc1 = 0.f;
#pragma unroll
            for (int dr = 0; dr < 3; ++dr) {
#pragma unroll
                for (int dc = 0; dc < 3; ++dc) {
                    const float ww = wk[dr * 3 + dc];
                    acc0 += ww * a[dr][dc];
                    acc1 += ww * a[dr][dc + 1];
                }
            }
            f2 v2 = {acc0, acc1};
            __builtin_nontemporal_store(
                v2, (f2*)(op + ((size_t)k * HO + r) * WO) + l);
        }
    }
}

extern "C" void kernel_launch(void* const* d_in, const int* in_sizes, int n_in,
                              void* d_out, int out_size, void* d_ws, size_t ws_size,
                              hipStream_t stream) {
    const float* x  = (const float*)d_in[0];   // [16,64,128,128] f32
    const float* Wt = (const float*)d_in[1];   // [8,9] f32
    float* out = (float*)d_out;                // [16,512,126,126] f32

    dim3 grid(9, C_, B_);   // (bands, channels, batch)
    conv_silu_kernel<<<grid, 256, 0, stream>>>(x, Wt, out);
}

// Round 3
// 116.625 us; speedup vs baseline: 1.4683x; 1.4683x over previous
//
#include <hip/hip_runtime.h>

// Problem constants (fixed by the reference setup)
#define B_   16
#define C_   64
#define H_   128
#define W_   128
#define HO   126
#define WO   126
#define NK   8     // number of conv kernels
#define ROWS 14    // output rows per block (126 = 9 * 14)
#define INR  16    // input rows staged = ROWS + 2

// Block = (band, channel, batch), 512 threads = 8 waves.
// Wave w owns output kernel-plane k=w for the whole band: it writes a single
// contiguous, monotonically ascending 7 KB stream (14 rows x 504 B).
// Lane l computes wo = l and wo = 64+l via a rolling 3-row tap window held in
// registers (6 LDS reads per row). Weights live in SGPRs (readfirstlane'd
// wave index -> scalar loads), so v_fma uses SGPR*VGPR.
__global__ __launch_bounds__(512) void conv_silu_kernel(
    const float* __restrict__ x, const float* __restrict__ Wt,
    float* __restrict__ out)
{
    __shared__ float s[INR][W_];   // 16 * 128 * 4 B = 8 KiB

    const int band = blockIdx.x;   // 0..8
    const int c    = blockIdx.y;   // 0..63
    const int b    = blockIdx.z;   // 0..15
    const int tid  = threadIdx.x;  // 0..511
    const int ho0  = band * ROWS;

    // ---- stage input band (16 rows x 128 cols) with SiLU applied ----
    // 2048 floats = 512 float4; one per thread. Always in-bounds
    // (ho0 max = 112, +15 = 127 = H-1).
    {
        const float4* xv =
            (const float4*)(x + ((size_t)(b * C_ + c) * H_ + ho0) * W_);
        const float4 v = xv[tid];
        const int row = tid >> 5;            // 32 float4 per row
        const int col = (tid & 31) << 2;
        float4 sv;
        sv.x = v.x * __builtin_amdgcn_rcpf(1.0f + __expf(-v.x));
        sv.y = v.y * __builtin_amdgcn_rcpf(1.0f + __expf(-v.y));
        sv.z = v.z * __builtin_amdgcn_rcpf(1.0f + __expf(-v.z));
        sv.w = v.w * __builtin_amdgcn_rcpf(1.0f + __expf(-v.w));
        *(float4*)&s[row][col] = sv;         // ds_write_b128
    }
    __syncthreads();

    // ---- compute: wave w handles kernel k = w ----
    const int l  = tid & 63;
    const int ws = __builtin_amdgcn_readfirstlane((int)(threadIdx.x >> 6)); // SGPR

    float w9[9];  // scalar loads (uniform address) -> SGPRs
#pragma unroll
    for (int j = 0; j < 9; ++j) w9[j] = Wt[ws * 9 + j];

    float* op = out + ((size_t)((b * C_ + c) * NK + ws) * HO + ho0) * WO;

    // Rolling tap window: t*[j][d] = silu(x)[input row r+j][wo + d]
    float tA[3][3], tB[3][3];
#pragma unroll
    for (int j = 0; j < 3; ++j) {
#pragma unroll
        for (int d = 0; d < 3; ++d) {
            tA[j][d] = s[j][l + d];                // cols 0..65, in-bounds
            tB[j][d] = s[j][(64 + l + d) & 127];   // masked lanes read junk, ok
        }
    }

#pragma unroll
    for (int r = 0; r < ROWS; ++r) {
        float accA = 0.f, accB = 0.f;
#pragma unroll
        for (int j = 0; j < 3; ++j) {
#pragma unroll
            for (int d = 0; d < 3; ++d) {
                const float ww = w9[j * 3 + d];
                accA += ww * tA[j][d];
                accB += ww * tB[j][d];
            }
        }
        op[r * WO + l] = accA;                     // wo = 0..63
        if (l < 62) op[r * WO + 64 + l] = accB;    // wo = 64..125

        if (r < ROWS - 1) {
            // rotate window and pull in input row r+3 (max 15 = INR-1)
#pragma unroll
            for (int j = 0; j < 2; ++j) {
#pragma unroll
                for (int d = 0; d < 3; ++d) {
                    tA[j][d] = tA[j + 1][d];
                    tB[j][d] = tB[j + 1][d];
                }
            }
#pragma unroll
            for (int d = 0; d < 3; ++d) {
                tA[2][d] = s[r + 3][l + d];
                tB[2][d] = s[r + 3][(64 + l + d) & 127];
            }
        }
    }
}

extern "C" void kernel_launch(void* const* d_in, const int* in_sizes, int n_in,
                              void* d_out, int out_size, void* d_ws, size_t ws_size,
                              hipStream_t stream) {
    const float* x  = (const float*)d_in[0];   // [16,64,128,128] f32
    const float* Wt = (const float*)d_in[1];   // [8,9] f32
    float* out = (float*)d_out;                // [16,512,126,126] f32

    dim3 grid(9, C_, B_);   // (bands, channels, batch)
    conv_silu_kernel<<<grid, 512, 0, stream>>>(x, Wt, out);
}